// Round 4
// baseline (1909.388 us; speedup 1.0000x reference)
//
#include <hip/hip_runtime.h>
#include <hip/hip_bf16.h>

// SimpleRNN: B=64, S=2048, IN=256, H=128, OUT=3 (all fp32)
// Phase 1: xproj = x @ W_xh^T + b_xh -> d_ws (64 MiB)  [byte-identical, ~230us]
// Phase 2: scan, 64 blocks x 128 threads (2 waves), 1 LDS-only barrier/step.
//   Round-3 post-mortem: VGPR_Count=88 -> compiler STILL re-loaded the
//   (loop-invariant) weights from global every step: ~1024 VMEM instr/CU/step
//   ~= the observed 1294 cyc/step. Fix: pin all 128 weight components through
//   empty `asm volatile("+v")` -- asm-defined values cannot be rematerialized
//   from memory, forcing true VGPR residency (budget 512 @ 1 wave/EU).

#define RNN_B   64
#define RNN_S   2048
#define RNN_IN  256
#define RNN_H   128
#define RNN_OUT 3

// ---------------------------------------------------------------------------
// Phase 1: fp32 tiled GEMM  C[M=131072, N=128] = A[M,256] * B[128,256]^T
// (byte-identical to rounds 2/3 for attribution)
// ---------------------------------------------------------------------------
__global__ __launch_bounds__(256) void xproj_gemm(
    const float* __restrict__ x, const float* __restrict__ Wxh,
    const float* __restrict__ bxh, float* __restrict__ xp) {
  __shared__ __align__(16) float As[32][132];  // [k][m]
  __shared__ __align__(16) float Bs[32][132];  // [k][n]

  const int tid = threadIdx.x;
  const int m0 = blockIdx.x * 128;
  const int tn = (tid & 15) * 8;   // n offset 0..120
  const int tm = (tid >> 4) * 8;   // m offset 0..120

  float acc[8][8];
#pragma unroll
  for (int i = 0; i < 8; ++i)
#pragma unroll
    for (int j = 0; j < 8; ++j) acc[i][j] = 0.f;

  const int c = (tid & 7) * 4;   // k sub-col (float4)
  const int r0 = tid >> 3;       // row 0..31

  for (int kc = 0; kc < RNN_IN; kc += 32) {
#pragma unroll
    for (int p = 0; p < 4; ++p) {
      const int row = r0 + 32 * p;
      const float4 va = *(const float4*)&x[(size_t)(m0 + row) * RNN_IN + kc + c];
      As[c + 0][row] = va.x; As[c + 1][row] = va.y;
      As[c + 2][row] = va.z; As[c + 3][row] = va.w;
      const float4 vb = *(const float4*)&Wxh[(size_t)row * RNN_IN + kc + c];
      Bs[c + 0][row] = vb.x; Bs[c + 1][row] = vb.y;
      Bs[c + 2][row] = vb.z; Bs[c + 3][row] = vb.w;
    }
    __syncthreads();
#pragma unroll
    for (int k = 0; k < 32; ++k) {
      const float4 a0 = *(const float4*)&As[k][tm];
      const float4 a1 = *(const float4*)&As[k][tm + 4];
      const float4 b0 = *(const float4*)&Bs[k][tn];
      const float4 b1 = *(const float4*)&Bs[k][tn + 4];
      const float a[8] = {a0.x, a0.y, a0.z, a0.w, a1.x, a1.y, a1.z, a1.w};
      const float b[8] = {b0.x, b0.y, b0.z, b0.w, b1.x, b1.y, b1.z, b1.w};
#pragma unroll
      for (int i = 0; i < 8; ++i)
#pragma unroll
        for (int j = 0; j < 8; ++j) acc[i][j] += a[i] * b[j];
    }
    __syncthreads();
  }

#pragma unroll
  for (int i = 0; i < 8; ++i) {
    const size_t row = (size_t)(m0 + tm + i);
#pragma unroll
    for (int j = 0; j < 8; j += 4) {
      float4 v;
      v.x = acc[i][j + 0] + bxh[tn + j + 0];
      v.y = acc[i][j + 1] + bxh[tn + j + 1];
      v.z = acc[i][j + 2] + bxh[tn + j + 2];
      v.w = acc[i][j + 3] + bxh[tn + j + 3];
      *(float4*)&xp[row * RNN_H + tn + j] = v;
    }
  }
}

// fast tanh: 1 - 2/(exp(2x)+1); saturates correctly at +-inf
__device__ __forceinline__ float fast_tanh(float a) {
  const float e = __expf(2.f * a);
  return 1.f - 2.f / (e + 1.f);
}

// LDS-only barrier: does NOT drain vmcnt (HIP __syncthreads emits vmcnt(0)),
// so global prefetch loads stay in flight across the barrier.
__device__ __forceinline__ void block_sync_lds() {
  asm volatile("s_waitcnt lgkmcnt(0)" ::: "memory");
  __builtin_amdgcn_s_barrier();
}

#define RNN_W_LIST(M) \
  M(0)  M(1)  M(2)  M(3)  M(4)  M(5)  M(6)  M(7)  \
  M(8)  M(9)  M(10) M(11) M(12) M(13) M(14) M(15) \
  M(16) M(17) M(18) M(19) M(20) M(21) M(22) M(23) \
  M(24) M(25) M(26) M(27) M(28) M(29) M(30) M(31)

// 128 weight components as named scalars, PINNED via empty asm: an
// asm-defined value cannot be rematerialized by re-loading from memory,
// so the allocator must keep them in VGPRs (rounds 2-3: VGPR_Count 92/88
// proved both array and named-float4 forms were re-loaded every step).
#define WDECL(i) float w##i##_0, w##i##_1, w##i##_2, w##i##_3;
#define WLOAD(i)                                                        \
  {                                                                     \
    const float4 _t = wrow[i];                                          \
    w##i##_0 = _t.x; w##i##_1 = _t.y; w##i##_2 = _t.z; w##i##_3 = _t.w; \
    asm volatile("" : "+v"(w##i##_0), "+v"(w##i##_1),                   \
                      "+v"(w##i##_2), "+v"(w##i##_3));                  \
  }

#define WFMA(i, a) {                              \
    const float4 h4 = hb_in[i];                   \
    a = fmaf(w##i##_0, h4.x, a);                  \
    a = fmaf(w##i##_1, h4.y, a);                  \
    a = fmaf(w##i##_2, h4.z, a);                  \
    a = fmaf(w##i##_3, h4.w, a);                  \
  }

#define RNN_MATVEC \
  WFMA(0,  acc0) WFMA(1,  acc1) WFMA(2,  acc2) WFMA(3,  acc3) \
  WFMA(4,  acc0) WFMA(5,  acc1) WFMA(6,  acc2) WFMA(7,  acc3) \
  WFMA(8,  acc0) WFMA(9,  acc1) WFMA(10, acc2) WFMA(11, acc3) \
  WFMA(12, acc0) WFMA(13, acc1) WFMA(14, acc2) WFMA(15, acc3) \
  WFMA(16, acc0) WFMA(17, acc1) WFMA(18, acc2) WFMA(19, acc3) \
  WFMA(20, acc0) WFMA(21, acc1) WFMA(22, acc2) WFMA(23, acc3) \
  WFMA(24, acc0) WFMA(25, acc1) WFMA(26, acc2) WFMA(27, acc3) \
  WFMA(28, acc0) WFMA(29, acc1) WFMA(30, acc2) WFMA(31, acc3)

// One step: broadcast ds_read_b128 of old h from BIN, matvec from pinned
// VGPRs, tanh, write h[j] to BOUT, single LDS-only barrier. PREG consumed
// then refilled with xp[TNEXT] (stays in flight ~4 steps).
#define RNN_STEP(BIN, BOUT, PREG, TNEXT)                              \
  {                                                                   \
    const float4* hb_in = (const float4*)(BIN);                       \
    float acc0 = bias + PREG, acc1 = 0.f, acc2 = 0.f, acc3 = 0.f;     \
    PREG = xpb[(size_t)(TNEXT) * RNN_H + j];                          \
    RNN_MATVEC                                                        \
    (BOUT)[j] = fast_tanh((acc0 + acc1) + (acc2 + acc3));             \
    block_sync_lds();                                                 \
  }

// ---------------------------------------------------------------------------
// Phase 2: recurrence. grid=64 blocks, block=128 threads (2 waves).
// Thread j owns output row j; W_hh row j pinned in 128 VGPRs.
// h double-buffered in LDS; 1 barrier/step; 4-deep global prefetch.
// ---------------------------------------------------------------------------
__global__ __launch_bounds__(128, 1)
__attribute__((amdgpu_waves_per_eu(1)))
void rnn_scan(
    const float* __restrict__ xp, const float* __restrict__ Whh,
    const float* __restrict__ bhh, const float* __restrict__ bh,
    const float* __restrict__ Wfc, const float* __restrict__ bfc,
    float* __restrict__ out) {
  const int b = blockIdx.x;
  const int j = threadIdx.x;  // 0..127 = output row

  __shared__ __align__(16) float hsA[RNN_H];
  __shared__ __align__(16) float hsB[RNN_H];

  const float4* wrow = (const float4*)&Whh[(size_t)j * RNN_H];
  RNN_W_LIST(WDECL)
  RNN_W_LIST(WLOAD)

  const float bias = bhh[j] + bh[j];

  hsA[j] = 0.f;
  block_sync_lds();

  const float* xpb = xp + (size_t)b * RNN_S * RNN_H;

  // 4-deep prefetch, one register per unrolled body (no shifting movs)
  float p0 = xpb[0 * RNN_H + j];
  float p1 = xpb[1 * RNN_H + j];
  float p2 = xpb[2 * RNN_H + j];
  float p3 = xpb[3 * RNN_H + j];

#pragma unroll 1
  for (int t = 0; t < RNN_S; t += 4) {
    const int n0 = (t + 4 < RNN_S) ? t + 4 : RNN_S - 1;
    const int n1 = (t + 5 < RNN_S) ? t + 5 : RNN_S - 1;
    const int n2 = (t + 6 < RNN_S) ? t + 6 : RNN_S - 1;
    const int n3 = (t + 7 < RNN_S) ? t + 7 : RNN_S - 1;
    RNN_STEP(hsA, hsB, p0, n0)
    RNN_STEP(hsB, hsA, p1, n1)
    RNN_STEP(hsA, hsB, p2, n2)
    RNN_STEP(hsB, hsA, p3, n3)
  }
  // final h is in hsA; trailing block_sync_lds made it visible.

  // fused FC: out[b][o] = sum_k hs[k] * Wfc[o][k] + bfc[o]
  if (j < RNN_OUT) {
    float s = bfc[j];
    const float4* hf = (const float4*)hsA;
#pragma unroll
    for (int k4 = 0; k4 < RNN_H / 4; ++k4) {
      const float4 wf = *(const float4*)&Wfc[(size_t)j * RNN_H + k4 * 4];
      const float4 h = hf[k4];
      s = fmaf(wf.x, h.x, s); s = fmaf(wf.y, h.y, s);
      s = fmaf(wf.z, h.z, s); s = fmaf(wf.w, h.w, s);
    }
    out[b * RNN_OUT + j] = s;
  }
}

extern "C" void kernel_launch(void* const* d_in, const int* in_sizes, int n_in,
                              void* d_out, int out_size, void* d_ws, size_t ws_size,
                              hipStream_t stream) {
  const float* x   = (const float*)d_in[0];
  const float* Wxh = (const float*)d_in[1];
  const float* bxh = (const float*)d_in[2];
  const float* Whh = (const float*)d_in[3];
  const float* bhh = (const float*)d_in[4];
  const float* bh  = (const float*)d_in[5];
  const float* Wfc = (const float*)d_in[6];
  const float* bfc = (const float*)d_in[7];
  float* out = (float*)d_out;
  float* xp  = (float*)d_ws;  // 131072*128*4 = 64 MiB

  xproj_gemm<<<dim3((RNN_B * RNN_S) / 128), dim3(256), 0, stream>>>(x, Wxh, bxh, xp);
  rnn_scan<<<dim3(RNN_B), dim3(128), 0, stream>>>(xp, Whh, bhh, bh, Wfc, bfc, out);
}

// Round 5
// 1180.545 us; speedup vs baseline: 1.6174x; 1.6174x over previous
//
#include <hip/hip_runtime.h>
#include <hip/hip_bf16.h>

// SimpleRNN: B=64, S=2048, IN=256, H=128, OUT=3 (all fp32)
// Phase 1: xproj = x @ W_xh^T + b_xh -> d_ws (64 MiB)  [byte-identical]
// Phase 2: scan, 64 blocks x 256 threads (4 waves), 1 LDS-only barrier/step.
//   Rounds 1-4 post-mortem: the register allocator NEVER grants >148 VGPRs
//   (148/92/88/84) regardless of hints/asm pins -- 128 weight floats per
//   thread always end up spill-reloaded from scratch each step. Fix: K-SPLIT.
//   Lane pair (2j,2j+1) owns row j; each thread keeps only 64 weight floats
//   (16 float4 ~= 95 VGPRs total -- inside the envelope the allocator has
//   honored). Pair-reduce with one in-wave __shfl_xor; still 1 barrier/step.

#define RNN_B   64
#define RNN_S   2048
#define RNN_IN  256
#define RNN_H   128
#define RNN_OUT 3

// ---------------------------------------------------------------------------
// Phase 1: fp32 tiled GEMM  C[M=131072, N=128] = A[M,256] * B[128,256]^T
// (byte-identical to rounds 2-4 for attribution)
// ---------------------------------------------------------------------------
__global__ __launch_bounds__(256) void xproj_gemm(
    const float* __restrict__ x, const float* __restrict__ Wxh,
    const float* __restrict__ bxh, float* __restrict__ xp) {
  __shared__ __align__(16) float As[32][132];  // [k][m]
  __shared__ __align__(16) float Bs[32][132];  // [k][n]

  const int tid = threadIdx.x;
  const int m0 = blockIdx.x * 128;
  const int tn = (tid & 15) * 8;   // n offset 0..120
  const int tm = (tid >> 4) * 8;   // m offset 0..120

  float acc[8][8];
#pragma unroll
  for (int i = 0; i < 8; ++i)
#pragma unroll
    for (int j = 0; j < 8; ++j) acc[i][j] = 0.f;

  const int c = (tid & 7) * 4;   // k sub-col (float4)
  const int r0 = tid >> 3;       // row 0..31

  for (int kc = 0; kc < RNN_IN; kc += 32) {
#pragma unroll
    for (int p = 0; p < 4; ++p) {
      const int row = r0 + 32 * p;
      const float4 va = *(const float4*)&x[(size_t)(m0 + row) * RNN_IN + kc + c];
      As[c + 0][row] = va.x; As[c + 1][row] = va.y;
      As[c + 2][row] = va.z; As[c + 3][row] = va.w;
      const float4 vb = *(const float4*)&Wxh[(size_t)row * RNN_IN + kc + c];
      Bs[c + 0][row] = vb.x; Bs[c + 1][row] = vb.y;
      Bs[c + 2][row] = vb.z; Bs[c + 3][row] = vb.w;
    }
    __syncthreads();
#pragma unroll
    for (int k = 0; k < 32; ++k) {
      const float4 a0 = *(const float4*)&As[k][tm];
      const float4 a1 = *(const float4*)&As[k][tm + 4];
      const float4 b0 = *(const float4*)&Bs[k][tn];
      const float4 b1 = *(const float4*)&Bs[k][tn + 4];
      const float a[8] = {a0.x, a0.y, a0.z, a0.w, a1.x, a1.y, a1.z, a1.w};
      const float b[8] = {b0.x, b0.y, b0.z, b0.w, b1.x, b1.y, b1.z, b1.w};
#pragma unroll
      for (int i = 0; i < 8; ++i)
#pragma unroll
        for (int j = 0; j < 8; ++j) acc[i][j] += a[i] * b[j];
    }
    __syncthreads();
  }

#pragma unroll
  for (int i = 0; i < 8; ++i) {
    const size_t row = (size_t)(m0 + tm + i);
#pragma unroll
    for (int j = 0; j < 8; j += 4) {
      float4 v;
      v.x = acc[i][j + 0] + bxh[tn + j + 0];
      v.y = acc[i][j + 1] + bxh[tn + j + 1];
      v.z = acc[i][j + 2] + bxh[tn + j + 2];
      v.w = acc[i][j + 3] + bxh[tn + j + 3];
      *(float4*)&xp[row * RNN_H + tn + j] = v;
    }
  }
}

// fast tanh: 1 - 2/(exp(2x)+1); saturates correctly at +-inf
__device__ __forceinline__ float fast_tanh(float a) {
  const float e = __expf(2.f * a);
  return 1.f - 2.f / (e + 1.f);
}

// LDS-only barrier: does NOT drain vmcnt (HIP __syncthreads emits vmcnt(0)),
// so global prefetch loads stay in flight across the barrier.
__device__ __forceinline__ void block_sync_lds() {
  asm volatile("s_waitcnt lgkmcnt(0)" ::: "memory");
  __builtin_amdgcn_s_barrier();
}

// 16 named float4 weight registers per thread (64 floats = half a W_hh row).
#define RNN_W_LIST(M) \
  M(0)  M(1)  M(2)  M(3)  M(4)  M(5)  M(6)  M(7)  \
  M(8)  M(9)  M(10) M(11) M(12) M(13) M(14) M(15)

#define WDECL(i) float4 w##i;
#define WLOAD(i) w##i = wrow[i];

#define WFMA(i, a) {                              \
    const float4 h4 = hb_in[i];                   \
    a = fmaf(w##i.x, h4.x, a);                    \
    a = fmaf(w##i.y, h4.y, a);                    \
    a = fmaf(w##i.z, h4.z, a);                    \
    a = fmaf(w##i.w, h4.w, a);                    \
  }

#define RNN_MATVEC \
  WFMA(0,  acc0) WFMA(1,  acc1) WFMA(2,  acc2) WFMA(3,  acc3) \
  WFMA(4,  acc0) WFMA(5,  acc1) WFMA(6,  acc2) WFMA(7,  acc3) \
  WFMA(8,  acc0) WFMA(9,  acc1) WFMA(10, acc2) WFMA(11, acc3) \
  WFMA(12, acc0) WFMA(13, acc1) WFMA(14, acc2) WFMA(15, acc3)

// One step: each thread reads ITS 64-float half of old h from BIN
// (2 distinct addresses per wave-instr -> conflict-free), 64 FMAs from
// register weights, in-wave pair reduction via shfl_xor(1), tanh, lane
// half==0 writes h[j] to BOUT, single LDS-only barrier. PREG consumed
// early then refilled with xp[TNEXT] (stays in flight ~4 steps).
#define RNN_STEP(BIN, BOUT, PREG, TNEXT)                              \
  {                                                                   \
    const float4* hb_in = (const float4*)(BIN) + 16 * half;           \
    const float xin = PREG;                                           \
    PREG = xpb[(size_t)(TNEXT) * RNN_H + j];                          \
    float acc0 = 0.f, acc1 = 0.f, acc2 = 0.f, acc3 = 0.f;             \
    RNN_MATVEC                                                        \
    float part = (acc0 + acc1) + (acc2 + acc3);                       \
    part += __shfl_xor(part, 1, 64);                                  \
    const float hv = fast_tanh(bias + xin + part);                    \
    if (half == 0) (BOUT)[j] = hv;                                    \
    block_sync_lds();                                                 \
  }

// ---------------------------------------------------------------------------
// Phase 2: recurrence. grid=64 blocks, block=256 threads (4 waves).
// Lane pair (2j,2j+1) owns row j; thread holds W_hh[j, 64*half..+63] in regs.
// h double-buffered in LDS; 1 barrier/step; 4-deep global prefetch.
// ---------------------------------------------------------------------------
__global__ __launch_bounds__(256, 1) void rnn_scan(
    const float* __restrict__ xp, const float* __restrict__ Whh,
    const float* __restrict__ bhh, const float* __restrict__ bh,
    const float* __restrict__ Wfc, const float* __restrict__ bfc,
    float* __restrict__ out) {
  const int b = blockIdx.x;
  const int t = threadIdx.x;   // 0..255
  const int j = t >> 1;        // row 0..127 (pair-owned)
  const int half = t & 1;      // which 64-wide K-half

  __shared__ __align__(16) float hsA[RNN_H];
  __shared__ __align__(16) float hsB[RNN_H];

  const float4* wrow = (const float4*)&Whh[(size_t)j * RNN_H + 64 * half];
  RNN_W_LIST(WDECL)
  RNN_W_LIST(WLOAD)

  const float bias = bhh[j] + bh[j];

  if (t < RNN_H) hsA[t] = 0.f;
  block_sync_lds();

  const float* xpb = xp + (size_t)b * RNN_S * RNN_H;

  // 4-deep prefetch, one register per unrolled body (no shifting movs).
  // Lane pair loads the same dword -> wave covers 32 consecutive dwords.
  float p0 = xpb[0 * RNN_H + j];
  float p1 = xpb[1 * RNN_H + j];
  float p2 = xpb[2 * RNN_H + j];
  float p3 = xpb[3 * RNN_H + j];

#pragma unroll 1
  for (int tstep = 0; tstep < RNN_S; tstep += 4) {
    const int n0 = (tstep + 4 < RNN_S) ? tstep + 4 : RNN_S - 1;
    const int n1 = (tstep + 5 < RNN_S) ? tstep + 5 : RNN_S - 1;
    const int n2 = (tstep + 6 < RNN_S) ? tstep + 6 : RNN_S - 1;
    const int n3 = (tstep + 7 < RNN_S) ? tstep + 7 : RNN_S - 1;
    RNN_STEP(hsA, hsB, p0, n0)
    RNN_STEP(hsB, hsA, p1, n1)
    RNN_STEP(hsA, hsB, p2, n2)
    RNN_STEP(hsB, hsA, p3, n3)
  }
  // 2048 steps: last body writes hsA; trailing block_sync_lds made it visible.

  // fused FC: out[b][o] = sum_k hs[k] * Wfc[o][k] + bfc[o]
  if (t < RNN_OUT) {
    float s = bfc[t];
    const float4* hf = (const float4*)hsA;
#pragma unroll
    for (int k4 = 0; k4 < RNN_H / 4; ++k4) {
      const float4 wf = *(const float4*)&Wfc[(size_t)t * RNN_H + k4 * 4];
      const float4 h = hf[k4];
      s = fmaf(wf.x, h.x, s); s = fmaf(wf.y, h.y, s);
      s = fmaf(wf.z, h.z, s); s = fmaf(wf.w, h.w, s);
    }
    out[b * RNN_OUT + t] = s;
  }
}

extern "C" void kernel_launch(void* const* d_in, const int* in_sizes, int n_in,
                              void* d_out, int out_size, void* d_ws, size_t ws_size,
                              hipStream_t stream) {
  const float* x   = (const float*)d_in[0];
  const float* Wxh = (const float*)d_in[1];
  const float* bxh = (const float*)d_in[2];
  const float* Whh = (const float*)d_in[3];
  const float* bhh = (const float*)d_in[4];
  const float* bh  = (const float*)d_in[5];
  const float* Wfc = (const float*)d_in[6];
  const float* bfc = (const float*)d_in[7];
  float* out = (float*)d_out;
  float* xp  = (float*)d_ws;  // 131072*128*4 = 64 MiB

  xproj_gemm<<<dim3((RNN_B * RNN_S) / 128), dim3(256), 0, stream>>>(x, Wxh, bxh, xp);
  rnn_scan<<<dim3(RNN_B), dim3(256), 0, stream>>>(xp, Whh, bhh, bh, Wfc, bfc, out);
}

// Round 6
// 1001.523 us; speedup vs baseline: 1.9065x; 1.1787x over previous
//
#include <hip/hip_runtime.h>
#include <hip/hip_bf16.h>

// SimpleRNN: B=64, S=2048, IN=256, H=128, OUT=3 (all fp32)
// Phase 1: xproj = x @ W_xh^T + b_xh -> d_ws (64 MiB)  [byte-identical]
// Phase 2: scan, 64 blocks x 512 threads (8 waves), 1 LDS-only barrier/step.
//   Round-5 post-mortem:
//   (a) VGPR_Count=52: allocator NEVER grants big flat arrays (5 rounds:
//       148/92/88/84/52) -> design UNDER the envelope: K-split-4, 8 float4
//       (32 weight floats) per thread, 4-lane group per row, 2x shfl_xor
//       reduction.
//   (b) SQ_LDS_BANK_CONFLICT=3.36e7 = 256 cyc/CU/step: the b128 half-offset
//       (256 B) aliased the same 4-bank group. Fix: XOR-rotated read order
//       (i^q) -> the 4 quarter-addresses per instr hit disjoint bank groups.

#define RNN_B   64
#define RNN_S   2048
#define RNN_IN  256
#define RNN_H   128
#define RNN_OUT 3

// ---------------------------------------------------------------------------
// Phase 1: fp32 tiled GEMM  C[M=131072, N=128] = A[M,256] * B[128,256]^T
// (byte-identical to rounds 2-5 for attribution)
// ---------------------------------------------------------------------------
__global__ __launch_bounds__(256) void xproj_gemm(
    const float* __restrict__ x, const float* __restrict__ Wxh,
    const float* __restrict__ bxh, float* __restrict__ xp) {
  __shared__ __align__(16) float As[32][132];  // [k][m]
  __shared__ __align__(16) float Bs[32][132];  // [k][n]

  const int tid = threadIdx.x;
  const int m0 = blockIdx.x * 128;
  const int tn = (tid & 15) * 8;   // n offset 0..120
  const int tm = (tid >> 4) * 8;   // m offset 0..120

  float acc[8][8];
#pragma unroll
  for (int i = 0; i < 8; ++i)
#pragma unroll
    for (int j = 0; j < 8; ++j) acc[i][j] = 0.f;

  const int c = (tid & 7) * 4;   // k sub-col (float4)
  const int r0 = tid >> 3;       // row 0..31

  for (int kc = 0; kc < RNN_IN; kc += 32) {
#pragma unroll
    for (int p = 0; p < 4; ++p) {
      const int row = r0 + 32 * p;
      const float4 va = *(const float4*)&x[(size_t)(m0 + row) * RNN_IN + kc + c];
      As[c + 0][row] = va.x; As[c + 1][row] = va.y;
      As[c + 2][row] = va.z; As[c + 3][row] = va.w;
      const float4 vb = *(const float4*)&Wxh[(size_t)row * RNN_IN + kc + c];
      Bs[c + 0][row] = vb.x; Bs[c + 1][row] = vb.y;
      Bs[c + 2][row] = vb.z; Bs[c + 3][row] = vb.w;
    }
    __syncthreads();
#pragma unroll
    for (int k = 0; k < 32; ++k) {
      const float4 a0 = *(const float4*)&As[k][tm];
      const float4 a1 = *(const float4*)&As[k][tm + 4];
      const float4 b0 = *(const float4*)&Bs[k][tn];
      const float4 b1 = *(const float4*)&Bs[k][tn + 4];
      const float a[8] = {a0.x, a0.y, a0.z, a0.w, a1.x, a1.y, a1.z, a1.w};
      const float b[8] = {b0.x, b0.y, b0.z, b0.w, b1.x, b1.y, b1.z, b1.w};
#pragma unroll
      for (int i = 0; i < 8; ++i)
#pragma unroll
        for (int j = 0; j < 8; ++j) acc[i][j] += a[i] * b[j];
    }
    __syncthreads();
  }

#pragma unroll
  for (int i = 0; i < 8; ++i) {
    const size_t row = (size_t)(m0 + tm + i);
#pragma unroll
    for (int j = 0; j < 8; j += 4) {
      float4 v;
      v.x = acc[i][j + 0] + bxh[tn + j + 0];
      v.y = acc[i][j + 1] + bxh[tn + j + 1];
      v.z = acc[i][j + 2] + bxh[tn + j + 2];
      v.w = acc[i][j + 3] + bxh[tn + j + 3];
      *(float4*)&xp[row * RNN_H + tn + j] = v;
    }
  }
}

// fast tanh: 1 - 2/(exp(2x)+1); saturates correctly at +-inf
__device__ __forceinline__ float fast_tanh(float a) {
  const float e = __expf(2.f * a);
  return 1.f - 2.f / (e + 1.f);
}

// LDS-only barrier: does NOT drain vmcnt (HIP __syncthreads emits vmcnt(0)),
// so global prefetch loads stay in flight across the barrier.
__device__ __forceinline__ void block_sync_lds() {
  asm volatile("s_waitcnt lgkmcnt(0)" ::: "memory");
  __builtin_amdgcn_s_barrier();
}

// 8 named float4 weight registers per thread (32 floats = quarter W_hh row).
#define RNN_W_LIST(M) M(0) M(1) M(2) M(3) M(4) M(5) M(6) M(7)

#define WDECL(i) float4 w##i;
// XOR-rotated load order matches the rotated h-read order below.
#define WLOAD(i) w##i = wrow[(i) ^ q];

#define WFMA(i, a) {                              \
    const float4 h4 = hq[(i) ^ q];                \
    a = fmaf(w##i.x, h4.x, a);                    \
    a = fmaf(w##i.y, h4.y, a);                    \
    a = fmaf(w##i.z, h4.z, a);                    \
    a = fmaf(w##i.w, h4.w, a);                    \
  }

#define RNN_MATVEC \
  WFMA(0, acc0) WFMA(1, acc1) WFMA(2, acc2) WFMA(3, acc3) \
  WFMA(4, acc0) WFMA(5, acc1) WFMA(6, acc2) WFMA(7, acc3)

// One step: thread (row r, quarter q) reads its 32-float K-quarter of old h
// from BIN with XOR-rotated b128s (4 unique addrs -> disjoint bank groups,
// 16-lane broadcast each: zero conflicts), 32 FMAs from register weights,
// 4-lane butterfly reduction (2x shfl_xor), tanh, q==0 lane writes h[r] to
// BOUT, single LDS-only barrier. PREG consumed early then refilled with
// xp[TNEXT] (stays in flight ~4 steps; barrier never drains vmcnt).
#define RNN_STEP(BIN, BOUT, PREG, TNEXT)                              \
  {                                                                   \
    const float4* hq = (const float4*)(BIN) + 8 * q;                  \
    const float xin = PREG;                                           \
    PREG = xpb[(size_t)(TNEXT) * RNN_H + r];                          \
    float acc0 = 0.f, acc1 = 0.f, acc2 = 0.f, acc3 = 0.f;             \
    RNN_MATVEC                                                        \
    float part = (acc0 + acc1) + (acc2 + acc3);                       \
    part += __shfl_xor(part, 1, 64);                                  \
    part += __shfl_xor(part, 2, 64);                                  \
    const float hv = fast_tanh(bias + xin + part);                    \
    if (q == 0) (BOUT)[r] = hv;                                       \
    block_sync_lds();                                                 \
  }

// ---------------------------------------------------------------------------
// Phase 2: recurrence. grid=64 blocks, block=512 threads (8 waves).
// Aligned 4-lane group owns row r = 16*wave + (lane>>2); thread holds
// W_hh[r, 32q..32q+31] in 8 float4 regs (~60 VGPRs total need).
// h double-buffered in LDS; 1 barrier/step; 4-deep global prefetch.
// ---------------------------------------------------------------------------
__global__ __launch_bounds__(512, 2) void rnn_scan(
    const float* __restrict__ xp, const float* __restrict__ Whh,
    const float* __restrict__ bhh, const float* __restrict__ bh,
    const float* __restrict__ Wfc, const float* __restrict__ bfc,
    float* __restrict__ out) {
  const int b = blockIdx.x;
  const int tid = threadIdx.x;        // 0..511
  const int wave = tid >> 6;          // 0..7
  const int lane = tid & 63;
  const int q = lane & 3;             // K-quarter 0..3
  const int r = wave * 16 + (lane >> 2);  // row 0..127

  __shared__ __align__(16) float hsA[RNN_H];
  __shared__ __align__(16) float hsB[RNN_H];

  const float4* wrow = (const float4*)&Whh[(size_t)r * RNN_H + 32 * q];
  RNN_W_LIST(WDECL)
  RNN_W_LIST(WLOAD)

  const float bias = bhh[r] + bh[r];

  if (tid < RNN_H) hsA[tid] = 0.f;
  block_sync_lds();

  const float* xpb = xp + (size_t)b * RNN_S * RNN_H;

  // 4-deep prefetch, one register per unrolled body (no shifting movs).
  float p0 = xpb[0 * RNN_H + r];
  float p1 = xpb[1 * RNN_H + r];
  float p2 = xpb[2 * RNN_H + r];
  float p3 = xpb[3 * RNN_H + r];

#pragma unroll 1
  for (int t = 0; t < RNN_S; t += 4) {
    const int n0 = (t + 4 < RNN_S) ? t + 4 : RNN_S - 1;
    const int n1 = (t + 5 < RNN_S) ? t + 5 : RNN_S - 1;
    const int n2 = (t + 6 < RNN_S) ? t + 6 : RNN_S - 1;
    const int n3 = (t + 7 < RNN_S) ? t + 7 : RNN_S - 1;
    RNN_STEP(hsA, hsB, p0, n0)
    RNN_STEP(hsB, hsA, p1, n1)
    RNN_STEP(hsA, hsB, p2, n2)
    RNN_STEP(hsB, hsA, p3, n3)
  }
  // 2048 steps: last body writes hsA; trailing block_sync_lds made it visible.

  // fused FC: out[b][o] = sum_k hs[k] * Wfc[o][k] + bfc[o]
  if (tid < RNN_OUT) {
    float s = bfc[tid];
    const float4* hf = (const float4*)hsA;
#pragma unroll
    for (int k4 = 0; k4 < RNN_H / 4; ++k4) {
      const float4 wf = *(const float4*)&Wfc[(size_t)tid * RNN_H + k4 * 4];
      const float4 h = hf[k4];
      s = fmaf(wf.x, h.x, s); s = fmaf(wf.y, h.y, s);
      s = fmaf(wf.z, h.z, s); s = fmaf(wf.w, h.w, s);
    }
    out[b * RNN_OUT + tid] = s;
  }
}

extern "C" void kernel_launch(void* const* d_in, const int* in_sizes, int n_in,
                              void* d_out, int out_size, void* d_ws, size_t ws_size,
                              hipStream_t stream) {
  const float* x   = (const float*)d_in[0];
  const float* Wxh = (const float*)d_in[1];
  const float* bxh = (const float*)d_in[2];
  const float* Whh = (const float*)d_in[3];
  const float* bhh = (const float*)d_in[4];
  const float* bh  = (const float*)d_in[5];
  const float* Wfc = (const float*)d_in[6];
  const float* bfc = (const float*)d_in[7];
  float* out = (float*)d_out;
  float* xp  = (float*)d_ws;  // 131072*128*4 = 64 MiB

  xproj_gemm<<<dim3((RNN_B * RNN_S) / 128), dim3(256), 0, stream>>>(x, Wxh, bxh, xp);
  rnn_scan<<<dim3(RNN_B), dim3(512), 0, stream>>>(xp, Whh, bhh, bh, Wfc, bfc, out);
}